// Round 1
// baseline (2538.242 us; speedup 1.0000x reference)
//
#include <hip/hip_runtime.h>
#include <math.h>

// ws layout (float offsets)
#define ZB_OFF   0          // Zbuf [2][8][256][256] = 1048576 floats
#define E_OFF    1048576    // e    [128][2048]      = 262144 floats
#define YP_OFF   1310720    // ypart[8][64][128][16] = 1048576 floats
#define FLAG_OFF 2359296    // flags[8][32] uint
// total ~9.44 MB

__device__ __forceinline__ float fast_tanh(float x) {
  x = fminf(fmaxf(x, -15.f), 15.f);
  float ex = __expf(2.f * x);
  return __fdividef(ex - 1.f, ex + 1.f);
}

// release/acquire barrier among the 32 blocks of one channel group
__device__ __forceinline__ void group_barrier(unsigned* flags, int slot, unsigned target) {
  __syncthreads();
  if (threadIdx.x < 64) {
    if (threadIdx.x == 0) {
      __threadfence();  // agent fence: drain + L2 writeback so our tile/y stores are visible
      __hip_atomic_store(&flags[slot], target, __ATOMIC_RELAXED, __HIP_MEMORY_SCOPE_AGENT);
    }
    if (threadIdx.x < 32) {
      int spins = 0;
      while (__hip_atomic_load(&flags[threadIdx.x], __ATOMIC_RELAXED,
                               __HIP_MEMORY_SCOPE_AGENT) < target) {
        __builtin_amdgcn_s_sleep(1);
        if (++spins > (1 << 15)) break;   // safety: fail loud (wrong) rather than hang
      }
    }
    if (threadIdx.x == 0) __threadfence();  // acquire: invalidate stale L1/L2 lines
  }
  __syncthreads();
}

// ---------------- K0: zero flags + Zbuf[0], compute embed e = (X@W^T)*mask_coarse
__global__ __launch_bounds__(256) void prep_kernel(
    const float* __restrict__ X, const float* __restrict__ W_embed,
    const float* __restrict__ mask_coarse, float* __restrict__ ws)
{
  const int tid = threadIdx.x, bid = blockIdx.x;  // grid = 128
  float* Zb = ws + ZB_OFF;
  float* eb = ws + E_OFF;
  unsigned* flags = (unsigned*)(ws + FLAG_OFF);
  if (bid == 0 && tid < 256) flags[tid] = 0;

  // zero Zbuf[0]: 524288 floats, 4096 per block
  float4 z4 = make_float4(0.f, 0.f, 0.f, 0.f);
#pragma unroll
  for (int k = 0; k < 4; ++k)
    *(float4*)&Zb[(size_t)bid * 4096 + tid * 16 + k * 4] = z4;

  // embed: block handles 16 output rows (o), thread: one o x 8 t's
  const int o  = bid * 16 + (tid & 15);
  const int t0 = (tid >> 4) * 8;
  const float4* Wf4 = (const float4*)W_embed + (size_t)o * 128;
  const float4* Xf4 = (const float4*)X;
  float acc[8];
#pragma unroll
  for (int i = 0; i < 8; ++i) acc[i] = 0.f;
  for (int k4 = 0; k4 < 128; ++k4) {
    float4 wv = Wf4[k4];
#pragma unroll
    for (int tt = 0; tt < 8; ++tt) {
      float4 xv = Xf4[(size_t)(t0 + tt) * 128 + k4];
      acc[tt] = fmaf(wv.x, xv.x, fmaf(wv.y, xv.y, fmaf(wv.z, xv.z, fmaf(wv.w, xv.w, acc[tt]))));
    }
  }
  float mc = mask_coarse[o & 255];
#pragma unroll
  for (int tt = 0; tt < 8; ++tt)
    eb[(size_t)(t0 + tt) * 2048 + o] = acc[tt] * mc;
}

// ---------------- K1: persistent scan. 256 blocks = 8 ch x 32 tiles (64 rows x 32 cols)
__global__ __launch_bounds__(256, 2) void scan_kernel(
    const float* __restrict__ mask_fine, const float* __restrict__ W_deconv,
    const float* __restrict__ w1, const float* __restrict__ w2,
    const float* __restrict__ w_out, float* __restrict__ ws)
{
  __shared__ float zin[72 * 44];      // 72 rows x 40 cols (stride 44 pad)
  __shared__ float redbuf[256 * 33];  // readout reduction
  __shared__ float pb[8 * 33];

  const int tid  = threadIdx.x;
  const int bid  = blockIdx.x;
  const int ch   = bid >> 5;
  const int tile = bid & 31;
  const int tI = tile >> 3, tJ = tile & 7;
  const int r0 = tI << 6, c0 = tJ << 5;
  const int lr = tid >> 3;          // 0..31
  const int lc = (tid & 7) << 2;    // 0,4..28

  float* Zb = ws + ZB_OFF;
  const float* eb = ws + E_OFF;
  float* yp = ws + YP_OFF;
  unsigned* flags = (unsigned*)(ws + FLAG_OFF) + ch * 32;

  // per-thread fixed constants (same (a,b) position every step)
  const int a16 = lr & 15;
  const int b16 = lc & 15;
  const int i0  = (r0 + lr) >> 4;
  const int jj  = (c0 + lc) >> 4;
  float4 wd[8];
#pragma unroll
  for (int c = 0; c < 8; ++c)
    wd[c] = *(const float4*)&W_deconv[(((c * 8 + ch) * 16) + a16) * 16 + b16];
  float4 mf0 = *(const float4*)&mask_fine[(size_t)(r0 + lr) * 256 + c0 + lc];
  float4 mf1 = *(const float4*)&mask_fine[(size_t)(r0 + lr + 32) * 256 + c0 + lc];
  float4 wo[16];
#pragma unroll
  for (int oc = 0; oc < 16; ++oc)
    wo[oc] = *(const float4*)&w_out[(((oc * 8 + ch) * 32) + lr) * 32 + lc];
  float w1s[9], w2s[25];
#pragma unroll
  for (int k = 0; k < 9; ++k)
    w1s[k] = __uint_as_float(__builtin_amdgcn_readfirstlane(__float_as_uint(w1[ch * 9 + k])));
#pragma unroll
  for (int k = 0; k < 25; ++k)
    w2s[k] = __uint_as_float(__builtin_amdgcn_readfirstlane(__float_as_uint(w2[ch * 25 + k])));

  auto load_row = [&](int zr, float* w) {
    float4 A  = *(const float4*)&zin[zr * 44 + lc];
    float4 B  = *(const float4*)&zin[zr * 44 + lc + 4];
    float4 Cq = *(const float4*)&zin[zr * 44 + lc + 8];
    w[0]=A.x; w[1]=A.y; w[2]=A.z; w[3]=A.w;
    w[4]=B.x; w[5]=B.y; w[6]=B.z; w[7]=B.w;
    w[8]=Cq.x; w[9]=Cq.y; w[10]=Cq.z; w[11]=Cq.w;
  };
  auto k2row = [&](const float* w, int a, float* c2a) {
#pragma unroll
    for (int j = 0; j < 4; ++j)
#pragma unroll
      for (int b = 0; b < 5; ++b)
        c2a[j] = fmaf(w[j + 2 * b], w2s[a * 5 + b], c2a[j]);
  };
  auto k1row = [&](const float* w, int a, float* c1a) {
#pragma unroll
    for (int j = 0; j < 4; ++j)
#pragma unroll
      for (int b = 0; b < 3; ++b)
        c1a[j] = fmaf(w[j + 3 + b], w1s[a * 3 + b], c1a[j]);
  };

  for (int t = 0; t < 128; ++t) {
    const float* Zold = Zb + (size_t)(t & 1) * 524288 + (size_t)ch * 65536;
    float*       Znew = Zb + (size_t)((t + 1) & 1) * 524288 + (size_t)ch * 65536;

    // ---- stage 72x40 tile+halo into LDS (circular wrap applied here)
    {
      const int cb = (tid & 7) * 5;
      const int rr = tid >> 3;
#pragma unroll
      for (int pass = 0; pass < 2; ++pass) {
        int r = pass * 32 + rr;
        int grow2 = (r0 - 4 + r) & 255;
#pragma unroll
        for (int k = 0; k < 5; ++k) {
          int gcol2 = (c0 - 4 + cb + k) & 255;
          zin[r * 44 + cb + k] = Zold[grow2 * 256 + gcol2];
        }
      }
      if (tid < 64) {
        int r = 64 + rr;
        int grow2 = (r0 - 4 + r) & 255;
#pragma unroll
        for (int k = 0; k < 5; ++k) {
          int gcol2 = (c0 - 4 + cb + k) & 255;
          zin[r * 44 + cb + k] = Zold[grow2 * 256 + gcol2];
        }
      }
    }

    // input-path e values for this step (L3-resident, issued before the sync)
    float ev[2][8];
#pragma unroll
    for (int h = 0; h < 2; ++h) {
      int ih = i0 + 2 * h;
#pragma unroll
      for (int c = 0; c < 8; ++c)
        ev[h][c] = eb[(size_t)t * 2048 + c * 256 + ih * 16 + jj];
    }

    __syncthreads();

    float racc[32];
#pragma unroll
    for (int h = 0; h < 2; ++h) {
      const int lrh = lr + 32 * h;
      float c1a[4] = {0,0,0,0}, c2a[4] = {0,0,0,0};
      float wrow[12];
      load_row(lrh + 0, wrow); k2row(wrow, 0, c2a);
      load_row(lrh + 2, wrow); k2row(wrow, 1, c2a);
      load_row(lrh + 3, wrow); k1row(wrow, 0, c1a);
      load_row(lrh + 4, wrow); k1row(wrow, 1, c1a); k2row(wrow, 2, c2a);
      load_row(lrh + 5, wrow); k1row(wrow, 2, c1a);
      load_row(lrh + 6, wrow); k2row(wrow, 3, c2a);
      load_row(lrh + 8, wrow); k2row(wrow, 4, c2a);

      const float* mfp = (h == 0) ? (const float*)&mf0 : (const float*)&mf1;
      float zv[4];
#pragma unroll
      for (int j = 0; j < 4; ++j) {
        float u = 0.f;
#pragma unroll
        for (int c = 0; c < 8; ++c)
          u = fmaf(ev[h][c], ((const float*)&wd[c])[j], u);
        float val = fmaf(0.9f, c1a[j], fmaf(0.1f, c2a[j], mfp[j] * u));
        zv[j] = fast_tanh(val);
      }
      *(float4*)&Znew[(size_t)(r0 + lrh) * 256 + c0 + lc] =
          make_float4(zv[0], zv[1], zv[2], zv[3]);
#pragma unroll
      for (int oc = 0; oc < 16; ++oc) {
        const float* wop = (const float*)&wo[oc];
        racc[h * 16 + oc] =
            fmaf(zv[0], wop[0], fmaf(zv[1], wop[1], fmaf(zv[2], wop[2], zv[3] * wop[3])));
      }
    }

    // ---- per-step readout reduction: 256 threads x 32 (patch,oc) -> 32 values
#pragma unroll
    for (int k = 0; k < 32; ++k) redbuf[tid * 33 + k] = racc[k];
    __syncthreads();
    {
      int col = tid & 31, chunk = tid >> 5;
      float s = 0.f;
#pragma unroll
      for (int r = 0; r < 32; ++r) s += redbuf[(chunk * 32 + r) * 33 + col];
      pb[chunk * 33 + col] = s;
    }
    __syncthreads();
    if (tid < 32) {
      float s = 0.f;
#pragma unroll
      for (int k = 0; k < 8; ++k) s += pb[k * 33 + tid];
      int p = tid >> 4, oc = tid & 15;
      yp[(((size_t)ch * 64 + (2 * tI + p) * 8 + tJ) * 128 + t) * 16 + oc] = s;
    }

    if (t < 127) group_barrier(flags, tile, (unsigned)(t + 1));
  }
}

// ---------------- K2: sum channel partials + bias -> out [128,16,8,8] flat
__global__ __launch_bounds__(256) void final_kernel(
    const float* __restrict__ b_out, const float* __restrict__ ws, float* __restrict__ out)
{
  int idx = blockIdx.x * 256 + threadIdx.x;  // 131072
  int t = idx >> 10;
  int rem = idx & 1023;
  int oc = rem >> 6;
  int IJ = rem & 63;
  const float* yp = ws + YP_OFF;
  float s = b_out[oc];
#pragma unroll
  for (int c = 0; c < 8; ++c)
    s += yp[(((size_t)c * 64 + IJ) * 128 + t) * 16 + oc];
  out[idx] = s;
}

extern "C" void kernel_launch(void* const* d_in, const int* in_sizes, int n_in,
                              void* d_out, int out_size, void* d_ws, size_t ws_size,
                              hipStream_t stream) {
  const float* X           = (const float*)d_in[0];
  const float* W_embed     = (const float*)d_in[1];
  const float* mask_coarse = (const float*)d_in[2];
  const float* mask_fine   = (const float*)d_in[3];
  const float* W_deconv    = (const float*)d_in[4];
  const float* w1          = (const float*)d_in[5];
  const float* w2          = (const float*)d_in[6];
  const float* w_out       = (const float*)d_in[7];
  const float* b_out       = (const float*)d_in[8];
  float* ws  = (float*)d_ws;
  float* out = (float*)d_out;

  prep_kernel<<<dim3(128), dim3(256), 0, stream>>>(X, W_embed, mask_coarse, ws);
  scan_kernel<<<dim3(256), dim3(256), 0, stream>>>(mask_fine, W_deconv, w1, w2, w_out, ws);
  final_kernel<<<dim3(512), dim3(256), 0, stream>>>(b_out, ws, out);
}

// Round 2
// 760.764 us; speedup vs baseline: 3.3364x; 3.3364x over previous
//
#include <hip/hip_runtime.h>
#include <math.h>

// ws layout (float offsets)
#define ZB_OFF   0          // Zbuf [2][8][256][256] = 1048576 floats
#define E_OFF    1048576    // e    [128][2048]      = 262144 floats
#define YP_OFF   1310720    // ypart[8][64][128][16] = 1048576 floats
#define FLAG_OFF 2359296    // flags[8][32] uint
// total ~9.44 MB

__device__ __forceinline__ float fast_tanh(float x) {
  x = fminf(fmaxf(x, -15.f), 15.f);
  float ex = __expf(2.f * x);
  return __fdividef(ex - 1.f, ex + 1.f);
}

// Cross-XCD coherent data path: relaxed AGENT-scope atomics are serviced at the
// coherent point (L2-bypass, L3/MALL-backed) — no buffer_wbl2 / buffer_inv needed.
__device__ __forceinline__ float2 aload_f2(const float* p) {
  unsigned long long v = __hip_atomic_load((const unsigned long long*)p,
                                           __ATOMIC_RELAXED, __HIP_MEMORY_SCOPE_AGENT);
  float2 r;
  r.x = __uint_as_float((unsigned)v);
  r.y = __uint_as_float((unsigned)(v >> 32));
  return r;
}
__device__ __forceinline__ void astore_f2(float* p, float a, float b) {
  unsigned long long v =
      ((unsigned long long)__float_as_uint(b) << 32) | (unsigned long long)__float_as_uint(a);
  __hip_atomic_store((unsigned long long*)p, v, __ATOMIC_RELAXED, __HIP_MEMORY_SCOPE_AGENT);
}

// barrier among the 32 blocks of one channel group.
// No __threadfence: data moves via agent-scope atomics (coherent at L3); the
// per-wave s_waitcnt vmcnt(0) that __syncthreads emits before s_barrier orders
// all of this block's data stores before the flag store.
__device__ __forceinline__ void group_barrier(unsigned* flags, int slot, unsigned target) {
  __syncthreads();
  if (threadIdx.x == 0)
    __hip_atomic_store(&flags[slot], target, __ATOMIC_RELAXED, __HIP_MEMORY_SCOPE_AGENT);
  if (threadIdx.x < 32) {
    int spins = 0;
    while (__hip_atomic_load(&flags[threadIdx.x], __ATOMIC_RELAXED,
                             __HIP_MEMORY_SCOPE_AGENT) < target) {
      __builtin_amdgcn_s_sleep(2);
      if (++spins > (1 << 20)) break;   // safety: fail loud (wrong) rather than hang
    }
  }
  __syncthreads();
}

// ---------------- K0: zero flags + Zbuf[0], compute embed e = (X@W^T)*mask_coarse
__global__ __launch_bounds__(256) void prep_kernel(
    const float* __restrict__ X, const float* __restrict__ W_embed,
    const float* __restrict__ mask_coarse, float* __restrict__ ws)
{
  const int tid = threadIdx.x, bid = blockIdx.x;  // grid = 128
  float* Zb = ws + ZB_OFF;
  float* eb = ws + E_OFF;
  unsigned* flags = (unsigned*)(ws + FLAG_OFF);
  if (bid == 0 && tid < 256) flags[tid] = 0;

  // zero Zbuf[0]: 524288 floats, 4096 per block
  float4 z4 = make_float4(0.f, 0.f, 0.f, 0.f);
#pragma unroll
  for (int k = 0; k < 4; ++k)
    *(float4*)&Zb[(size_t)bid * 4096 + tid * 16 + k * 4] = z4;

  // embed: block handles 16 output rows (o), thread: one o x 8 t's
  const int o  = bid * 16 + (tid & 15);
  const int t0 = (tid >> 4) * 8;
  const float4* Wf4 = (const float4*)W_embed + (size_t)o * 128;
  const float4* Xf4 = (const float4*)X;
  float acc[8];
#pragma unroll
  for (int i = 0; i < 8; ++i) acc[i] = 0.f;
  for (int k4 = 0; k4 < 128; ++k4) {
    float4 wv = Wf4[k4];
#pragma unroll
    for (int tt = 0; tt < 8; ++tt) {
      float4 xv = Xf4[(size_t)(t0 + tt) * 128 + k4];
      acc[tt] = fmaf(wv.x, xv.x, fmaf(wv.y, xv.y, fmaf(wv.z, xv.z, fmaf(wv.w, xv.w, acc[tt]))));
    }
  }
  float mc = mask_coarse[o & 255];
#pragma unroll
  for (int tt = 0; tt < 8; ++tt)
    eb[(size_t)(t0 + tt) * 2048 + o] = acc[tt] * mc;
}

// ---------------- K1: persistent scan. 256 blocks = 8 ch x 32 tiles (64 rows x 32 cols)
__global__ __launch_bounds__(256, 2) void scan_kernel(
    const float* __restrict__ mask_fine, const float* __restrict__ W_deconv,
    const float* __restrict__ w1, const float* __restrict__ w2,
    const float* __restrict__ w_out, float* __restrict__ ws)
{
  __shared__ float zin[72 * 44];      // 72 rows x 40 cols (stride 44 pad)
  __shared__ float redbuf[256 * 33];  // readout reduction
  __shared__ float pb[8 * 33];

  const int tid  = threadIdx.x;
  const int bid  = blockIdx.x;
  const int ch   = bid >> 5;
  const int tile = bid & 31;
  const int tI = tile >> 3, tJ = tile & 7;
  const int r0 = tI << 6, c0 = tJ << 5;
  const int lr = tid >> 3;          // 0..31
  const int lc = (tid & 7) << 2;    // 0,4..28

  float* Zb = ws + ZB_OFF;
  const float* eb = ws + E_OFF;
  float* yp = ws + YP_OFF;
  unsigned* flags = (unsigned*)(ws + FLAG_OFF) + ch * 32;

  // per-thread fixed constants (same (a,b) position every step)
  const int a16 = lr & 15;
  const int b16 = lc & 15;
  const int i0  = (r0 + lr) >> 4;
  const int jj  = (c0 + lc) >> 4;
  float4 wd[8];
#pragma unroll
  for (int c = 0; c < 8; ++c)
    wd[c] = *(const float4*)&W_deconv[(((c * 8 + ch) * 16) + a16) * 16 + b16];
  float4 mf0 = *(const float4*)&mask_fine[(size_t)(r0 + lr) * 256 + c0 + lc];
  float4 mf1 = *(const float4*)&mask_fine[(size_t)(r0 + lr + 32) * 256 + c0 + lc];
  float4 wo[16];
#pragma unroll
  for (int oc = 0; oc < 16; ++oc)
    wo[oc] = *(const float4*)&w_out[(((oc * 8 + ch) * 32) + lr) * 32 + lc];
  float w1s[9], w2s[25];
#pragma unroll
  for (int k = 0; k < 9; ++k)
    w1s[k] = __uint_as_float(__builtin_amdgcn_readfirstlane(__float_as_uint(w1[ch * 9 + k])));
#pragma unroll
  for (int k = 0; k < 25; ++k)
    w2s[k] = __uint_as_float(__builtin_amdgcn_readfirstlane(__float_as_uint(w2[ch * 25 + k])));

  auto load_row = [&](int zr, float* w) {
    float4 A  = *(const float4*)&zin[zr * 44 + lc];
    float4 B  = *(const float4*)&zin[zr * 44 + lc + 4];
    float4 Cq = *(const float4*)&zin[zr * 44 + lc + 8];
    w[0]=A.x; w[1]=A.y; w[2]=A.z; w[3]=A.w;
    w[4]=B.x; w[5]=B.y; w[6]=B.z; w[7]=B.w;
    w[8]=Cq.x; w[9]=Cq.y; w[10]=Cq.z; w[11]=Cq.w;
  };
  auto k2row = [&](const float* w, int a, float* c2a) {
#pragma unroll
    for (int j = 0; j < 4; ++j)
#pragma unroll
      for (int b = 0; b < 5; ++b)
        c2a[j] = fmaf(w[j + 2 * b], w2s[a * 5 + b], c2a[j]);
  };
  auto k1row = [&](const float* w, int a, float* c1a) {
#pragma unroll
    for (int j = 0; j < 4; ++j)
#pragma unroll
      for (int b = 0; b < 3; ++b)
        c1a[j] = fmaf(w[j + 3 + b], w1s[a * 3 + b], c1a[j]);
  };

  for (int t = 0; t < 128; ++t) {
    const float* Zold = Zb + (size_t)(t & 1) * 524288 + (size_t)ch * 65536;
    float*       Znew = Zb + (size_t)((t + 1) & 1) * 524288 + (size_t)ch * 65536;

    // ---- stage 72x40 tile+halo into LDS via coherent 8B atomic loads
    // 72 rows x 40 cols = 1440 float2; thread does up to 6
    {
#pragma unroll
      for (int k = 0; k < 6; ++k) {
        int u = tid + (k << 8);
        if (u < 1440) {
          int row = u / 20;          // 0..71
          int cp  = u - row * 20;    // 0..19
          int col = cp << 1;         // 0..38 (even)
          int grow = (r0 - 4 + row) & 255;
          int gcol = (c0 - 4 + col) & 255;   // even, pair stays contiguous
          float2 v = aload_f2(&Zold[grow * 256 + gcol]);
          *(float2*)&zin[row * 44 + col] = v;
        }
      }
    }

    // input-path e values for this step (L2-resident now — no more inv)
    float ev[2][8];
#pragma unroll
    for (int h = 0; h < 2; ++h) {
      int ih = i0 + 2 * h;
#pragma unroll
      for (int c = 0; c < 8; ++c)
        ev[h][c] = eb[(size_t)t * 2048 + c * 256 + ih * 16 + jj];
    }

    __syncthreads();

    float racc[32];
#pragma unroll
    for (int h = 0; h < 2; ++h) {
      const int lrh = lr + 32 * h;
      float c1a[4] = {0,0,0,0}, c2a[4] = {0,0,0,0};
      float wrow[12];
      load_row(lrh + 0, wrow); k2row(wrow, 0, c2a);
      load_row(lrh + 2, wrow); k2row(wrow, 1, c2a);
      load_row(lrh + 3, wrow); k1row(wrow, 0, c1a);
      load_row(lrh + 4, wrow); k1row(wrow, 1, c1a); k2row(wrow, 2, c2a);
      load_row(lrh + 5, wrow); k1row(wrow, 2, c1a);
      load_row(lrh + 6, wrow); k2row(wrow, 3, c2a);
      load_row(lrh + 8, wrow); k2row(wrow, 4, c2a);

      const float* mfp = (h == 0) ? (const float*)&mf0 : (const float*)&mf1;
      float zv[4];
#pragma unroll
      for (int j = 0; j < 4; ++j) {
        float u = 0.f;
#pragma unroll
        for (int c = 0; c < 8; ++c)
          u = fmaf(ev[h][c], ((const float*)&wd[c])[j], u);
        float val = fmaf(0.9f, c1a[j], fmaf(0.1f, c2a[j], mfp[j] * u));
        zv[j] = fast_tanh(val);
      }
      // coherent write of new state (2 x 8B atomic stores)
      float* dst = Znew + (size_t)(r0 + lrh) * 256 + c0 + lc;
      astore_f2(dst, zv[0], zv[1]);
      astore_f2(dst + 2, zv[2], zv[3]);
#pragma unroll
      for (int oc = 0; oc < 16; ++oc) {
        const float* wop = (const float*)&wo[oc];
        racc[h * 16 + oc] =
            fmaf(zv[0], wop[0], fmaf(zv[1], wop[1], fmaf(zv[2], wop[2], zv[3] * wop[3])));
      }
    }

    // ---- per-step readout reduction: 256 threads x 32 (patch,oc) -> 32 values
#pragma unroll
    for (int k = 0; k < 32; ++k) redbuf[tid * 33 + k] = racc[k];
    __syncthreads();
    {
      int col = tid & 31, chunk = tid >> 5;
      float s = 0.f;
#pragma unroll
      for (int r = 0; r < 32; ++r) s += redbuf[(chunk * 32 + r) * 33 + col];
      pb[chunk * 33 + col] = s;
    }
    __syncthreads();
    if (tid < 32) {
      float s = 0.f;
#pragma unroll
      for (int k = 0; k < 8; ++k) s += pb[k * 33 + tid];
      int p = tid >> 4, oc = tid & 15;
      yp[(((size_t)ch * 64 + (2 * tI + p) * 8 + tJ) * 128 + t) * 16 + oc] = s;
    }

    if (t < 127) group_barrier(flags, tile, (unsigned)(t + 1));
  }
}

// ---------------- K2: sum channel partials + bias -> out [128,16,8,8] flat
__global__ __launch_bounds__(256) void final_kernel(
    const float* __restrict__ b_out, const float* __restrict__ ws, float* __restrict__ out)
{
  int idx = blockIdx.x * 256 + threadIdx.x;  // 131072
  int t = idx >> 10;
  int rem = idx & 1023;
  int oc = rem >> 6;
  int IJ = rem & 63;
  const float* yp = ws + YP_OFF;
  float s = b_out[oc];
#pragma unroll
  for (int c = 0; c < 8; ++c)
    s += yp[(((size_t)c * 64 + IJ) * 128 + t) * 16 + oc];
  out[idx] = s;
}

extern "C" void kernel_launch(void* const* d_in, const int* in_sizes, int n_in,
                              void* d_out, int out_size, void* d_ws, size_t ws_size,
                              hipStream_t stream) {
  const float* X           = (const float*)d_in[0];
  const float* W_embed     = (const float*)d_in[1];
  const float* mask_coarse = (const float*)d_in[2];
  const float* mask_fine   = (const float*)d_in[3];
  const float* W_deconv    = (const float*)d_in[4];
  const float* w1          = (const float*)d_in[5];
  const float* w2          = (const float*)d_in[6];
  const float* w_out       = (const float*)d_in[7];
  const float* b_out       = (const float*)d_in[8];
  float* ws  = (float*)d_ws;
  float* out = (float*)d_out;

  prep_kernel<<<dim3(128), dim3(256), 0, stream>>>(X, W_embed, mask_coarse, ws);
  scan_kernel<<<dim3(256), dim3(256), 0, stream>>>(mask_fine, W_deconv, w1, w2, w_out, ws);
  final_kernel<<<dim3(512), dim3(256), 0, stream>>>(b_out, ws, out);
}

// Round 3
// 605.605 us; speedup vs baseline: 4.1913x; 1.2562x over previous
//
#include <hip/hip_runtime.h>
#include <math.h>

// ws layout (float offsets)
#define ZB_OFF   0          // Zstrip [2][8][256][256] (only 4-wide tile boundaries touched)
#define E_OFF    1048576    // e    [128][2048]      = 262144 floats
#define YP_OFF   1310720    // ypart[8][64][128][16] = 1048576 floats
#define FLAG_OFF 2359296    // flags[256][16] uint (64B-padded per block)

__device__ __forceinline__ float fast_tanh(float x) {
  x = fminf(fmaxf(x, -15.f), 15.f);
  float ex = __expf(2.f * x);
  return __fdividef(ex - 1.f, ex + 1.f);
}

// Cross-XCD coherent data path: relaxed AGENT-scope atomics are serviced at the
// coherent point (L2-bypass) — no buffer_wbl2 / buffer_inv needed.
__device__ __forceinline__ float2 aload_f2(const float* p) {
  unsigned long long v = __hip_atomic_load((const unsigned long long*)p,
                                           __ATOMIC_RELAXED, __HIP_MEMORY_SCOPE_AGENT);
  float2 r;
  r.x = __uint_as_float((unsigned)v);
  r.y = __uint_as_float((unsigned)(v >> 32));
  return r;
}
__device__ __forceinline__ void astore_f2(float* p, float a, float b) {
  unsigned long long v =
      ((unsigned long long)__float_as_uint(b) << 32) | (unsigned long long)__float_as_uint(a);
  __hip_atomic_store((unsigned long long*)p, v, __ATOMIC_RELAXED, __HIP_MEMORY_SCOPE_AGENT);
}

// ---------------- K0: zero flags, compute embed e = (X@W^T)*mask_coarse
__global__ __launch_bounds__(256) void prep_kernel(
    const float* __restrict__ X, const float* __restrict__ W_embed,
    const float* __restrict__ mask_coarse, float* __restrict__ ws)
{
  const int tid = threadIdx.x, bid = blockIdx.x;  // grid = 128
  float* eb = ws + E_OFF;
  unsigned* flags = (unsigned*)(ws + FLAG_OFF);
  if (bid < 16) flags[bid * 256 + tid] = 0;   // 256 blocks x 16 uints

  // embed: block handles 16 output rows (o), thread: one o x 8 t's
  const int o  = bid * 16 + (tid & 15);
  const int t0 = (tid >> 4) * 8;
  const float4* Wf4 = (const float4*)W_embed + (size_t)o * 128;
  const float4* Xf4 = (const float4*)X;
  float acc[8];
#pragma unroll
  for (int i = 0; i < 8; ++i) acc[i] = 0.f;
  for (int k4 = 0; k4 < 128; ++k4) {
    float4 wv = Wf4[k4];
#pragma unroll
    for (int tt = 0; tt < 8; ++tt) {
      float4 xv = Xf4[(size_t)(t0 + tt) * 128 + k4];
      acc[tt] = fmaf(wv.x, xv.x, fmaf(wv.y, xv.y, fmaf(wv.z, xv.z, fmaf(wv.w, xv.w, acc[tt]))));
    }
  }
  float mc = mask_coarse[o & 255];
#pragma unroll
  for (int tt = 0; tt < 8; ++tt)
    eb[(size_t)(t0 + tt) * 2048 + o] = acc[tt] * mc;
}

// ---------------- K1: persistent scan. 256 blocks = 8 ch x (4x8 tiles of 64x32)
// State lives in LDS; only 4-wide boundary ring is exchanged via coherent strips.
__global__ __launch_bounds__(256, 1) void scan_kernel(
    const float* __restrict__ mask_fine, const float* __restrict__ W_deconv,
    const float* __restrict__ w1, const float* __restrict__ w2,
    const float* __restrict__ w_out, float* __restrict__ ws)
{
  __shared__ float zin[72 * 44];      // persistent state tile + halo (stride 44)
  __shared__ float redbuf[256 * 33];  // readout reduction
  __shared__ float pb[8 * 33];

  const int tid  = threadIdx.x;
  const int bid  = blockIdx.x;
  const int ch   = bid >> 5;
  const int tile = bid & 31;
  const int tI = tile >> 3, tJ = tile & 7;   // 4 x 8 tile grid
  const int r0 = tI << 6, c0 = tJ << 5;
  const int lr = tid >> 3;          // 0..31
  const int lc = (tid & 7) << 2;    // 0,4..28

  float* Zb = ws + ZB_OFF;
  const float* eb = ws + E_OFF;
  float* yp = ws + YP_OFF;
  unsigned* flags_all = (unsigned*)(ws + FLAG_OFF);
  unsigned* myf = flags_all + bid * 16;

  // toroidal 8-neighborhood (circular conv wrap)
  unsigned* nfp = nullptr;
  if (tid < 8) {
    const int dI[8] = {-1, -1, -1, 0, 0, 1, 1, 1};
    const int dJ[8] = {-1, 0, 1, -1, 1, -1, 0, 1};
    int nI = (tI + dI[tid]) & 3;
    int nJ = (tJ + dJ[tid]) & 7;
    nfp = flags_all + (ch * 32 + nI * 8 + nJ) * 16;
  }

  // per-thread fixed constants (same (a,b) position every step)
  const int a16 = lr & 15;
  const int b16 = lc & 15;
  const int i0  = (r0 + lr) >> 4;
  const int jj  = (c0 + lc) >> 4;
  float4 wd[8];
#pragma unroll
  for (int c = 0; c < 8; ++c)
    wd[c] = *(const float4*)&W_deconv[(((c * 8 + ch) * 16) + a16) * 16 + b16];
  float4 mf0 = *(const float4*)&mask_fine[(size_t)(r0 + lr) * 256 + c0 + lc];
  float4 mf1 = *(const float4*)&mask_fine[(size_t)(r0 + lr + 32) * 256 + c0 + lc];
  float4 wo[16];
#pragma unroll
  for (int oc = 0; oc < 16; ++oc)
    wo[oc] = *(const float4*)&w_out[(((oc * 8 + ch) * 32) + lr) * 32 + lc];
  float w1s[9], w2s[25];
#pragma unroll
  for (int k = 0; k < 9; ++k)
    w1s[k] = __uint_as_float(__builtin_amdgcn_readfirstlane(__float_as_uint(w1[ch * 9 + k])));
#pragma unroll
  for (int k = 0; k < 25; ++k)
    w2s[k] = __uint_as_float(__builtin_amdgcn_readfirstlane(__float_as_uint(w2[ch * 25 + k])));

  // init persistent state (Z0 = 0, incl. halo)
  for (int k = tid; k < 72 * 44; k += 256) zin[k] = 0.f;
  __syncthreads();

  auto load_row = [&](int zr, float* w) {
    float4 A  = *(const float4*)&zin[zr * 44 + lc];
    float4 B  = *(const float4*)&zin[zr * 44 + lc + 4];
    float4 Cq = *(const float4*)&zin[zr * 44 + lc + 8];
    w[0]=A.x; w[1]=A.y; w[2]=A.z; w[3]=A.w;
    w[4]=B.x; w[5]=B.y; w[6]=B.z; w[7]=B.w;
    w[8]=Cq.x; w[9]=Cq.y; w[10]=Cq.z; w[11]=Cq.w;
  };
  auto k2row = [&](const float* w, int a, float* c2a) {
#pragma unroll
    for (int j = 0; j < 4; ++j)
#pragma unroll
      for (int b = 0; b < 5; ++b)
        c2a[j] = fmaf(w[j + 2 * b], w2s[a * 5 + b], c2a[j]);
  };
  auto k1row = [&](const float* w, int a, float* c1a) {
#pragma unroll
    for (int j = 0; j < 4; ++j)
#pragma unroll
      for (int b = 0; b < 3; ++b)
        c1a[j] = fmaf(w[j + 3 + b], w1s[a * 3 + b], c1a[j]);
  };

  for (int t = 0; t < 128; ++t) {
    float* Zstrip = Zb + (size_t)((t + 1) & 1) * 524288 + (size_t)ch * 65536;

    // input-path e values for this step (plain cached loads; eb is read-only)
    float ev[2][8];
#pragma unroll
    for (int h = 0; h < 2; ++h) {
      int ih = i0 + 2 * h;
#pragma unroll
      for (int c = 0; c < 8; ++c)
        ev[h][c] = eb[(size_t)t * 2048 + c * 256 + ih * 16 + jj];
    }

    // ---- compute Z_{t+1} into registers (reads zin = Z_t incl halo)
    float zvv[2][4];
    float racc[32];
#pragma unroll
    for (int h = 0; h < 2; ++h) {
      const int lrh = lr + 32 * h;
      float c1a[4] = {0,0,0,0}, c2a[4] = {0,0,0,0};
      float wrow[12];
      load_row(lrh + 0, wrow); k2row(wrow, 0, c2a);
      load_row(lrh + 2, wrow); k2row(wrow, 1, c2a);
      load_row(lrh + 3, wrow); k1row(wrow, 0, c1a);
      load_row(lrh + 4, wrow); k1row(wrow, 1, c1a); k2row(wrow, 2, c2a);
      load_row(lrh + 5, wrow); k1row(wrow, 2, c1a);
      load_row(lrh + 6, wrow); k2row(wrow, 3, c2a);
      load_row(lrh + 8, wrow); k2row(wrow, 4, c2a);

      const float* mfp = (h == 0) ? (const float*)&mf0 : (const float*)&mf1;
#pragma unroll
      for (int j = 0; j < 4; ++j) {
        float u = 0.f;
#pragma unroll
        for (int c = 0; c < 8; ++c)
          u = fmaf(ev[h][c], ((const float*)&wd[c])[j], u);
        float val = fmaf(0.9f, c1a[j], fmaf(0.1f, c2a[j], mfp[j] * u));
        zvv[h][j] = fast_tanh(val);
      }
#pragma unroll
      for (int oc = 0; oc < 16; ++oc) {
        const float* wop = (const float*)&wo[oc];
        racc[h * 16 + oc] =
            fmaf(zvv[h][0], wop[0],
                 fmaf(zvv[h][1], wop[1], fmaf(zvv[h][2], wop[2], zvv[h][3] * wop[3])));
      }
    }

    __syncthreads();  // all reads of Z_t from zin complete

    // ---- commit: interior -> LDS; boundary ring -> coherent strips
#pragma unroll
    for (int h = 0; h < 2; ++h) {
      const int lrh = lr + 32 * h;
      *(float4*)&zin[(4 + lrh) * 44 + 4 + lc] =
          make_float4(zvv[h][0], zvv[h][1], zvv[h][2], zvv[h][3]);
      bool bnd = (h == 0 ? (lr < 4) : (lr >= 28)) || (lc == 0) || (lc == 28);
      if (bnd) {
        float* dst = Zstrip + (size_t)(r0 + lrh) * 256 + c0 + lc;
        astore_f2(dst, zvv[h][0], zvv[h][1]);
        astore_f2(dst + 2, zvv[h][2], zvv[h][3]);
      }
    }

    __syncthreads();  // per-wave vmcnt(0) before barrier: strip stores are drained

    // arrive early — neighbors can proceed while we do the readout reduction
    if (t < 127 && tid == 0)
      __hip_atomic_store(myf, (unsigned)(t + 1), __ATOMIC_RELAXED, __HIP_MEMORY_SCOPE_AGENT);

    // ---- per-step readout reduction: 256 threads x 32 (patch,oc) -> 32 values
#pragma unroll
    for (int k = 0; k < 32; ++k) redbuf[tid * 33 + k] = racc[k];
    __syncthreads();
    {
      int col = tid & 31, chunk = tid >> 5;
      float s = 0.f;
#pragma unroll
      for (int r = 0; r < 32; ++r) s += redbuf[(chunk * 32 + r) * 33 + col];
      pb[chunk * 33 + col] = s;
    }
    __syncthreads();
    if (tid < 32) {
      float s = 0.f;
#pragma unroll
      for (int k = 0; k < 8; ++k) s += pb[k * 33 + tid];
      int p = tid >> 4, oc = tid & 15;
      yp[(((size_t)ch * 64 + (2 * tI + p) * 8 + tJ) * 128 + t) * 16 + oc] = s;
    }

    if (t < 127) {
      // wait for the 8 toroidal neighbors to publish step t+1 strips
      if (tid < 8) {
        int spins = 0;
        while (__hip_atomic_load(nfp, __ATOMIC_RELAXED, __HIP_MEMORY_SCOPE_AGENT) <
               (unsigned)(t + 1)) {
          __builtin_amdgcn_s_sleep(1);
          if (++spins > (1 << 20)) break;  // fail loud rather than hang
        }
      }
      __syncthreads();

      // ---- load halo ring (832 floats = 416 f2) from neighbors' strips
#pragma unroll
      for (int pass = 0; pass < 2; ++pass) {
        int u = tid + (pass << 8);
        if (u < 416) {
          int zr, zc;
          if (u < 80)       { zr = u / 20;            zc = (u % 20) << 1; }            // top
          else if (u < 160) { int v = u - 80;  zr = 68 + v / 20; zc = (v % 20) << 1; } // bottom
          else if (u < 288) { int v = u - 160; zr = 4 + (v >> 1); zc = (v & 1) << 1; } // left
          else              { int v = u - 288; zr = 4 + (v >> 1); zc = 36 + ((v & 1) << 1); } // right
          int grow = (r0 - 4 + zr) & 255;
          int gcol = (c0 - 4 + zc) & 255;
          float2 v2 = aload_f2(&Zstrip[(size_t)grow * 256 + gcol]);
          *(float2*)&zin[zr * 44 + zc] = v2;
        }
      }
      __syncthreads();
    }
  }
}

// ---------------- K2: sum channel partials + bias -> out [128,16,8,8] flat
__global__ __launch_bounds__(256) void final_kernel(
    const float* __restrict__ b_out, const float* __restrict__ ws, float* __restrict__ out)
{
  int idx = blockIdx.x * 256 + threadIdx.x;  // 131072
  int t = idx >> 10;
  int rem = idx & 1023;
  int oc = rem >> 6;
  int IJ = rem & 63;
  const float* yp = ws + YP_OFF;
  float s = b_out[oc];
#pragma unroll
  for (int c = 0; c < 8; ++c)
    s += yp[(((size_t)c * 64 + IJ) * 128 + t) * 16 + oc];
  out[idx] = s;
}

extern "C" void kernel_launch(void* const* d_in, const int* in_sizes, int n_in,
                              void* d_out, int out_size, void* d_ws, size_t ws_size,
                              hipStream_t stream) {
  const float* X           = (const float*)d_in[0];
  const float* W_embed     = (const float*)d_in[1];
  const float* mask_coarse = (const float*)d_in[2];
  const float* mask_fine   = (const float*)d_in[3];
  const float* W_deconv    = (const float*)d_in[4];
  const float* w1          = (const float*)d_in[5];
  const float* w2          = (const float*)d_in[6];
  const float* w_out       = (const float*)d_in[7];
  const float* b_out       = (const float*)d_in[8];
  float* ws  = (float*)d_ws;
  float* out = (float*)d_out;

  prep_kernel<<<dim3(128), dim3(256), 0, stream>>>(X, W_embed, mask_coarse, ws);
  scan_kernel<<<dim3(256), dim3(256), 0, stream>>>(mask_fine, W_deconv, w1, w2, w_out, ws);
  final_kernel<<<dim3(512), dim3(256), 0, stream>>>(b_out, ws, out);
}